// Round 8
// baseline (269.838 us; speedup 1.0000x reference)
//
#include <hip/hip_runtime.h>
#include <math.h>

// Problem constants
#define NG   12
#define NH   8
#define CIN  64
#define CQK  32
#define CVAL 32
#define COUT 64
#define NB   2
#define NN   512
#define NROWS (NB * NN)     // 1024
#define GHH  (NG * NH)      // 96 heads
#define DIN  (NG * CIN)     // 768
#define DQK  (GHH * CQK)    // 3072
#define DOUT (NG * COUT)    // 768

typedef __attribute__((ext_vector_type(8))) short bf16x8;
typedef __attribute__((ext_vector_type(4))) float f32x4;
typedef unsigned short ushort_t;

// ---------------------------------------------------------------------------
// split fp32 -> (hi, lo) bf16 planes.  x = hi + lo + O(2^-16 x).
// ---------------------------------------------------------------------------
__device__ __forceinline__ ushort_t bf16_rne(float v) {
    unsigned u = __float_as_uint(v);
    return (ushort_t)((u + 0x7fffu + ((u >> 16) & 1u)) >> 16);
}

// ---------------------------------------------------------------------------
// Fused prep: split feat + swizzle/split Wq,Wk,Wv (block-range dispatch).
// blocks [0,768): feat split; [768,1056): W swizzle (96 blocks per matrix).
// Wr layout [gp][o>>4][k>>3][o&15][k&7] -> a wave's B-frag load is one
// contiguous 1 KB read.
// ---------------------------------------------------------------------------
__global__ __launch_bounds__(256) void prep_kernel(
    const float* __restrict__ feat,
    const float* __restrict__ Wq, const float* __restrict__ Wk,
    const float* __restrict__ Wv,
    ushort_t* __restrict__ Xhi, ushort_t* __restrict__ Xlo,
    ushort_t* __restrict__ Wqh, ushort_t* __restrict__ Wql)
{
    const int bb = blockIdx.x;
    if (bb < 768) {
        const int i = bb * 256 + threadIdx.x;       // < 196608
        float4 x = ((const float4*)feat)[i];
        ushort_t h[4], l[4];
        float vv[4] = {x.x, x.y, x.z, x.w};
        #pragma unroll
        for (int c = 0; c < 4; ++c) {
            ushort_t hb = bf16_rne(vv[c]);
            float hf = __uint_as_float(((unsigned)hb) << 16);
            h[c] = hb;
            l[c] = bf16_rne(vv[c] - hf);
        }
        ((ushort4*)Xhi)[i] = make_ushort4(h[0], h[1], h[2], h[3]);
        ((ushort4*)Xlo)[i] = make_ushort4(l[0], l[1], l[2], l[3]);
    } else {
        const int zz = (bb - 768) / 96;
        const float* W = (zz == 0) ? Wq : (zz == 1) ? Wk : Wv;
        ushort_t* hi = Wqh + (size_t)zz * 196608;
        ushort_t* lo = Wql + (size_t)zz * 196608;
        const int t  = ((bb - 768) % 96) * 256 + threadIdx.x;   // [0, 24576)
        const int kc = t & 7;
        const int o  = (t >> 3) & 255;
        const int gp = t >> 11;
        const float* src = W + ((size_t)(gp * 256 + o)) * 64 + kc * 8;
        float v[8];
        *(float4*)v       = *(const float4*)src;
        *(float4*)(v + 4) = *(const float4*)(src + 4);
        ushort_t h8[8] __attribute__((aligned(16)));
        ushort_t l8[8] __attribute__((aligned(16)));
        #pragma unroll
        for (int j = 0; j < 8; ++j) {
            ushort_t hb = bf16_rne(v[j]);
            float hf = __uint_as_float(((unsigned)hb) << 16);
            h8[j] = hb;
            l8[j] = bf16_rne(v[j] - hf);
        }
        const size_t dst = ((size_t)(gp * 16 + (o >> 4)) * 8 + kc) * 128 + (o & 15) * 8;
        *(uint4*)(hi + dst) = *(const uint4*)h8;
        *(uint4*)(lo + dst) = *(const uint4*)l8;
    }
}

__global__ __launch_bounds__(256) void split_kernel(
    const float* __restrict__ in, ushort_t* __restrict__ hi,
    ushort_t* __restrict__ lo, int n4)
{
    int i = blockIdx.x * 256 + threadIdx.x;
    if (i >= n4) return;
    float4 x = ((const float4*)in)[i];
    ushort_t h[4], l[4];
    float vv[4] = {x.x, x.y, x.z, x.w};
    #pragma unroll
    for (int c = 0; c < 4; ++c) {
        ushort_t hb = bf16_rne(vv[c]);
        float hf = __uint_as_float(((unsigned)hb) << 16);
        h[c] = hb;
        l[c] = bf16_rne(vv[c] - hf);
    }
    ((ushort4*)hi)[i] = make_ushort4(h[0], h[1], h[2], h[3]);
    ((ushort4*)lo)[i] = make_ushort4(l[0], l[1], l[2], l[3]);
}

// ---------------------------------------------------------------------------
// Kernel 1: block-circulant QKV projection, split-bf16 MFMA.
// 128m x 64n block tile (wave tile 64x32) -> 1152 blocks = 4.5 blocks/CU.
// A: double-buffered LDS (1 barrier/k-step); B: direct global, pre-swizzled.
// ---------------------------------------------------------------------------
__global__ __launch_bounds__(256, 1) void qkv_mfma_kernel(
    const ushort_t* __restrict__ Xhi, const ushort_t* __restrict__ Xlo,
    const ushort_t* __restrict__ Wrh, const ushort_t* __restrict__ Wrl,
    float* __restrict__ qo, float* __restrict__ ko, float* __restrict__ vo)
{
    __shared__ __attribute__((aligned(16))) ushort_t As[2][2][128][40];
    const int z = blockIdx.z;
    float* __restrict__ out = (z == 0) ? qo : (z == 1) ? ko : vo;
    const ushort_t* Wh = Wrh + (size_t)z * 196608;
    const ushort_t* Wl = Wrl + (size_t)z * 196608;
    const int m0 = blockIdx.y * 128;
    const int c0 = blockIdx.x * 64;
    const int hg = c0 >> 8;
    const int o0 = c0 & 255;
    const int tid  = threadIdx.x;
    const int srow = tid & 127;
    const int spl  = tid >> 7;       // staging plane 0=hi 1=lo
    const int lane = tid & 63;
    const int w    = tid >> 6;
    const int wm   = (w >> 1) * 64;
    const int wn   = (w & 1) * 32;
    const int lm   = lane & 15;
    const int lq   = lane >> 4;
    const int ct0  = (o0 + wn) >> 4;

    f32x4 acc[4][2];
    #pragma unroll
    for (int i = 0; i < 4; ++i) { acc[i][0] = (f32x4)(0.0f); acc[i][1] = (f32x4)(0.0f); }

    const ushort_t* Xp = (spl ? Xlo : Xhi) + (size_t)(m0 + srow) * DIN;

    // prologue: stage k-chunk 0 into buffer 0
    {
        const uint4* pa = (const uint4*)Xp;
        uint4 a0 = pa[0], a1 = pa[1], a2 = pa[2], a3 = pa[3];
        *(uint4*)&As[0][spl][srow][0]  = a0;
        *(uint4*)&As[0][spl][srow][8]  = a1;
        *(uint4*)&As[0][spl][srow][16] = a2;
        *(uint4*)&As[0][spl][srow][24] = a3;
    }
    __syncthreads();
    int buf = 0;

    for (int ks = 0; ks < 24; ++ks) {
        uint4 nv0, nv1, nv2, nv3;
        if (ks < 23) {
            const uint4* pa = (const uint4*)(Xp + (ks + 1) * 32);
            nv0 = pa[0]; nv1 = pa[1]; nv2 = pa[2]; nv3 = pa[3];
        }
        const int g = ks >> 1;
        int gp = g - hg; if (gp < 0) gp += NG;
        // ---- B fragments: direct global, pre-swizzled (coalesced) ----
        const size_t bbase = ((size_t)(gp * 16 + ct0) * 8 + ((ks & 1) * 4 + lq)) * 128 + lm * 8;
        bf16x8 bh[2], bl[2];
        #pragma unroll
        for (int nt = 0; nt < 2; ++nt) {
            bh[nt] = *(const bf16x8*)(Wh + bbase + nt * 1024);
            bl[nt] = *(const bf16x8*)(Wl + bbase + nt * 1024);
        }
        // ---- A fragments from LDS ----
        bf16x8 ah[4], al[4];
        #pragma unroll
        for (int mt = 0; mt < 4; ++mt) {
            ah[mt] = *(const bf16x8*)&As[buf][0][wm + mt * 16 + lm][lq * 8];
            al[mt] = *(const bf16x8*)&As[buf][1][wm + mt * 16 + lm][lq * 8];
        }
        #pragma unroll
        for (int mt = 0; mt < 4; ++mt)
            #pragma unroll
            for (int nt = 0; nt < 2; ++nt) {
                acc[mt][nt] = __builtin_amdgcn_mfma_f32_16x16x32_bf16(ah[mt], bh[nt], acc[mt][nt], 0, 0, 0);
                acc[mt][nt] = __builtin_amdgcn_mfma_f32_16x16x32_bf16(ah[mt], bl[nt], acc[mt][nt], 0, 0, 0);
                acc[mt][nt] = __builtin_amdgcn_mfma_f32_16x16x32_bf16(al[mt], bh[nt], acc[mt][nt], 0, 0, 0);
            }
        if (ks < 23) {
            *(uint4*)&As[buf ^ 1][spl][srow][0]  = nv0;
            *(uint4*)&As[buf ^ 1][spl][srow][8]  = nv1;
            *(uint4*)&As[buf ^ 1][spl][srow][16] = nv2;
            *(uint4*)&As[buf ^ 1][spl][srow][24] = nv3;
            __syncthreads();
            buf ^= 1;
        }
    }
    #pragma unroll
    for (int mt = 0; mt < 4; ++mt)
        #pragma unroll
        for (int r = 0; r < 4; ++r) {
            float* dst = out + (size_t)(m0 + wm + mt * 16 + lq * 4 + r) * DQK + c0 + wn + lm;
            dst[0]  = acc[mt][0][r];
            dst[16] = acc[mt][1][r];
        }
}

// ---------------------------------------------------------------------------
// Kernel 2: RMSNorm + fused sequence-rope + platonic-rope (unchanged).
// ---------------------------------------------------------------------------
__global__ __launch_bounds__(256) void norm_rope_kernel(
    float* __restrict__ q, float* __restrict__ k,
    const float* __restrict__ coords,
    const int* __restrict__ seq,
    const float* __restrict__ qw,
    const float* __restrict__ kw,
    const float* __restrict__ pf)
{
    const int hid = blockIdx.x * 256 + threadIdx.x;
    const int gh = hid % GHH;
    const int bn = hid / GHH;
    const int g = gh >> 3;
    const int h = gh & 7;
    float* qp = q + (size_t)hid * CQK;
    float* kp = k + (size_t)hid * CQK;
    float xq[CQK], xk[CQK];
    #pragma unroll
    for (int u = 0; u < 8; ++u) *(float4*)(xq + 4 * u) = *(const float4*)(qp + 4 * u);
    #pragma unroll
    for (int u = 0; u < 8; ++u) *(float4*)(xk + 4 * u) = *(const float4*)(kp + 4 * u);

    float sq = 0.f, sk = 0.f;
    #pragma unroll
    for (int c = 0; c < CQK; ++c) { sq = fmaf(xq[c], xq[c], sq); sk = fmaf(xk[c], xk[c], sk); }
    const float eps = 1.1920928955078125e-07f;
    const float invq = rsqrtf(sq * (1.f / CQK) + eps);
    const float invk = rsqrtf(sk * (1.f / CQK) + eps);
    #pragma unroll
    for (int c = 0; c < CQK; ++c) { xq[c] *= invq * qw[c]; xk[c] *= invk * kw[c]; }

    const float pos = (float)seq[bn];
    const float cx = coords[bn * 3 + 0], cy = coords[bn * 3 + 1], cz = coords[bn * 3 + 2];
    float sg, cg;
    sincosf((float)g * 0.5235987755982988f, &sg, &cg);
    const float u0 = cg * cx + sg * cy;
    const float u1 = cg * cy - sg * cx;
    const float u2 = cz;

    #pragma unroll
    for (int f = 0; f < 16; ++f) {
        const float invf = exp2f(-(float)f * 0.8304820237218405f);
        const float* fr = pf + ((size_t)h * 16 + f) * 3;
        const float ang = fmaf(pos, invf, u0 * fr[0] + u1 * fr[1] + u2 * fr[2]);
        float sn, cs;
        sincosf(ang, &sn, &cs);
        float a1 = xq[2 * f], a2 = xq[2 * f + 1];
        xq[2 * f]     = a1 * cs - a2 * sn;
        xq[2 * f + 1] = a1 * sn + a2 * cs;
        float b1 = xk[2 * f], b2 = xk[2 * f + 1];
        xk[2 * f]     = b1 * cs - b2 * sn;
        xk[2 * f + 1] = b1 * sn + b2 * cs;
    }
    #pragma unroll
    for (int u = 0; u < 8; ++u) *(float4*)(qp + 4 * u) = *(const float4*)(xq + 4 * u);
    #pragma unroll
    for (int u = 0; u < 8; ++u) *(float4*)(kp + 4 * u) = *(const float4*)(xk + 4 * u);
}

// ---------------------------------------------------------------------------
// Kernel 3: MFMA flash attention (unchanged; split-AO epilogue).
// ---------------------------------------------------------------------------
__global__ __launch_bounds__(256, 1) void attn_mfma_kernel(
    const float* __restrict__ q,
    const float* __restrict__ k,
    const float* __restrict__ v,
    ushort_t* __restrict__ aoh,
    ushort_t* __restrict__ aol)
{
    __shared__ __attribute__((aligned(16))) ushort_t Kh[128][40];
    __shared__ __attribute__((aligned(16))) ushort_t Kl[128][40];
    __shared__ __attribute__((aligned(16))) ushort_t Vth[32][136];
    __shared__ __attribute__((aligned(16))) ushort_t Vtl[32][136];
    __shared__ __attribute__((aligned(16))) ushort_t Ps[128][136];

    const int gh    = blockIdx.x;
    const int chunk = blockIdx.y;
    const int b     = blockIdx.z;
    const size_t headoff = (size_t)b * NN * DQK + (size_t)gh * CQK;
    const int tid  = threadIdx.x;
    const int lane = tid & 63;
    const int w    = tid >> 6;
    const int lm   = lane & 15;
    const int lq   = lane >> 4;       // quad
    const int qloc = w * 32;          // wave's local q-row base (0..96)

    const float scale = 0.17677669529663687f;  // 1/sqrt(32)
    bf16x8 qh[2], ql[2];
    #pragma unroll
    for (int mt = 0; mt < 2; ++mt) {
        const int row = chunk * 128 + qloc + mt * 16 + lm;
        const float* qp = q + headoff + (size_t)row * DQK + lq * 8;
        float4 t0 = *(const float4*)qp;
        float4 t1 = *(const float4*)(qp + 4);
        float vals[8] = {t0.x, t0.y, t0.z, t0.w, t1.x, t1.y, t1.z, t1.w};
        short h8[8], l8[8];
        #pragma unroll
        for (int j = 0; j < 8; ++j) {
            float x = vals[j] * scale;
            ushort_t hb = bf16_rne(x);
            float hf = __uint_as_float(((unsigned)hb) << 16);
            h8[j] = (short)hb;
            l8[j] = (short)bf16_rne(x - hf);
        }
        qh[mt] = *(bf16x8*)h8;
        ql[mt] = *(bf16x8*)l8;
    }

    float mrun[2][4], lrun[2][4];
    f32x4 o[2][2];
    #pragma unroll
    for (int mt = 0; mt < 2; ++mt) {
        #pragma unroll
        for (int r = 0; r < 4; ++r) { mrun[mt][r] = -3.0e38f; lrun[mt][r] = 0.f; }
        o[mt][0] = (f32x4)(0.0f); o[mt][1] = (f32x4)(0.0f);
    }

    const int sr = tid >> 1;          // staging row 0..127
    const int sh = (tid & 1) * 16;    // staging col half

    for (int j0 = 0; j0 < NN; j0 += 128) {
        const float* kp = k + headoff + (size_t)(j0 + sr) * DQK + sh;
        const float* vp = v + headoff + (size_t)(j0 + sr) * DQK + sh;
        float kb[16], vb[16];
        #pragma unroll
        for (int u = 0; u < 4; ++u) *(float4*)(kb + 4 * u) = *(const float4*)(kp + 4 * u);
        #pragma unroll
        for (int u = 0; u < 4; ++u) *(float4*)(vb + 4 * u) = *(const float4*)(vp + 4 * u);
        __syncthreads();   // previous iteration's PV reads done
        ushort_t kh16[16] __attribute__((aligned(16)));
        ushort_t kl16[16] __attribute__((aligned(16)));
        #pragma unroll
        for (int i = 0; i < 16; ++i) {
            ushort_t hb = bf16_rne(kb[i]);
            float hf = __uint_as_float(((unsigned)hb) << 16);
            kh16[i] = hb;
            kl16[i] = bf16_rne(kb[i] - hf);
            ushort_t vh = bf16_rne(vb[i]);
            float vf = __uint_as_float(((unsigned)vh) << 16);
            Vth[sh + i][sr] = vh;
            Vtl[sh + i][sr] = bf16_rne(vb[i] - vf);
        }
        *(uint4*)&Kh[sr][sh]     = *(uint4*)&kh16[0];
        *(uint4*)&Kh[sr][sh + 8] = *(uint4*)&kh16[8];
        *(uint4*)&Kl[sr][sh]     = *(uint4*)&kl16[0];
        *(uint4*)&Kl[sr][sh + 8] = *(uint4*)&kl16[8];
        __syncthreads();

        f32x4 sf[2][8];
        #pragma unroll
        for (int nt = 0; nt < 8; ++nt) {
            bf16x8 bh = *(const bf16x8*)&Kh[nt * 16 + lm][lq * 8];
            bf16x8 bl = *(const bf16x8*)&Kl[nt * 16 + lm][lq * 8];
            #pragma unroll
            for (int mt = 0; mt < 2; ++mt) {
                f32x4 s = (f32x4)(0.0f);
                s = __builtin_amdgcn_mfma_f32_16x16x32_bf16(qh[mt], bh, s, 0, 0, 0);
                s = __builtin_amdgcn_mfma_f32_16x16x32_bf16(qh[mt], bl, s, 0, 0, 0);
                s = __builtin_amdgcn_mfma_f32_16x16x32_bf16(ql[mt], bh, s, 0, 0, 0);
                sf[mt][nt] = s;
            }
        }

        #pragma unroll
        for (int mt = 0; mt < 2; ++mt) {
            float cr[4];
            #pragma unroll
            for (int r = 0; r < 4; ++r) {
                float t = sf[mt][0][r];
                #pragma unroll
                for (int nt = 1; nt < 8; ++nt) t = fmaxf(t, sf[mt][nt][r]);
                t = fmaxf(t, __shfl_xor(t, 1, 64));
                t = fmaxf(t, __shfl_xor(t, 2, 64));
                t = fmaxf(t, __shfl_xor(t, 4, 64));
                t = fmaxf(t, __shfl_xor(t, 8, 64));
                const float mn = fmaxf(mrun[mt][r], t);
                cr[r] = __expf(mrun[mt][r] - mn);
                mrun[mt][r] = mn;
                lrun[mt][r] *= cr[r];
            }
            o[mt][0] *= f32x4{cr[0], cr[1], cr[2], cr[3]};
            o[mt][1] *= f32x4{cr[0], cr[1], cr[2], cr[3]};
            float rsum[4] = {0.f, 0.f, 0.f, 0.f};
            #pragma unroll
            for (int nt = 0; nt < 8; ++nt) {
                #pragma unroll
                for (int r = 0; r < 4; ++r) {
                    const float p = __expf(sf[mt][nt][r] - mrun[mt][r]);
                    rsum[r] += p;
                    Ps[qloc + mt * 16 + lq * 4 + r][nt * 16 + lm] = bf16_rne(p);
                }
            }
            #pragma unroll
            for (int r = 0; r < 4; ++r) {
                float t = rsum[r];
                t += __shfl_xor(t, 1, 64);
                t += __shfl_xor(t, 2, 64);
                t += __shfl_xor(t, 4, 64);
                t += __shfl_xor(t, 8, 64);
                lrun[mt][r] += t;
            }
        }
        __syncthreads();

        #pragma unroll
        for (int kt = 0; kt < 4; ++kt) {
            bf16x8 pa[2];
            #pragma unroll
            for (int mt = 0; mt < 2; ++mt)
                pa[mt] = *(const bf16x8*)&Ps[qloc + mt * 16 + lm][kt * 32 + lq * 8];
            #pragma unroll
            for (int vt = 0; vt < 2; ++vt) {
                bf16x8 bvh = *(const bf16x8*)&Vth[vt * 16 + lm][kt * 32 + lq * 8];
                bf16x8 bvl = *(const bf16x8*)&Vtl[vt * 16 + lm][kt * 32 + lq * 8];
                #pragma unroll
                for (int mt = 0; mt < 2; ++mt) {
                    o[mt][vt] = __builtin_amdgcn_mfma_f32_16x16x32_bf16(pa[mt], bvh, o[mt][vt], 0, 0, 0);
                    o[mt][vt] = __builtin_amdgcn_mfma_f32_16x16x32_bf16(pa[mt], bvl, o[mt][vt], 0, 0, 0);
                }
            }
        }
    }

    // ---- epilogue: normalize + split-bf16 store ----
    #pragma unroll
    for (int mt = 0; mt < 2; ++mt) {
        float inv[4];
        #pragma unroll
        for (int r = 0; r < 4; ++r) inv[r] = 1.f / lrun[mt][r];
        #pragma unroll
        for (int r = 0; r < 4; ++r) {
            const int row = chunk * 128 + qloc + mt * 16 + lq * 4 + r;
            const size_t off = headoff + (size_t)row * DQK + lm;
            const float x0 = o[mt][0][r] * inv[r];
            const float x1 = o[mt][1][r] * inv[r];
            const ushort_t h0 = bf16_rne(x0);
            const ushort_t h1 = bf16_rne(x1);
            aoh[off]      = h0;
            aoh[off + 16] = h1;
            aol[off]      = bf16_rne(x0 - __uint_as_float(((unsigned)h0) << 16));
            aol[off + 16] = bf16_rne(x1 - __uint_as_float(((unsigned)h1) << 16));
        }
    }
}

// ---------------------------------------------------------------------------
// Kernel 4: output projection, split-bf16 MFMA, split-K=8.
// ---------------------------------------------------------------------------
__global__ __launch_bounds__(256, 1) void oproj_mfma_kernel(
    const ushort_t* __restrict__ Ahi, const ushort_t* __restrict__ Alo,   // [1024][3072]
    const ushort_t* __restrict__ Wohi, const ushort_t* __restrict__ Wolo, // [12][64][256]
    float* __restrict__ part)                                             // [8][1024][768]
{
    __shared__ __attribute__((aligned(16))) ushort_t As[2][128][40];
    __shared__ __attribute__((aligned(16))) ushort_t Bs[2][64][40];
    const int h  = blockIdx.x;
    const int m0 = blockIdx.y * 128;
    const int kz = blockIdx.z;
    const int tid  = threadIdx.x;
    const int srow = tid & 127;
    const int spl  = tid >> 7;
    const int lane = tid & 63;
    const int w    = tid >> 6;
    const int wm   = (w >> 1) * 64;
    const int wn   = (w & 1) * 32;
    const int lm   = lane & 15;
    const int lq   = lane >> 4;

    f32x4 acc[4][2];
    #pragma unroll
    for (int i = 0; i < 4; ++i) { acc[i][0] = (f32x4)(0.0f); acc[i][1] = (f32x4)(0.0f); }

    const ushort_t* Ap = (spl ? Alo : Ahi) + (size_t)(m0 + srow) * DQK;
    const int brow = tid & 63;
    const int bpl  = (tid >> 6) & 1;
    const ushort_t* Wp = (bpl ? Wolo : Wohi);

    for (int ks = 0; ks < 12; ++ks) {
        const int kk = kz * 384 + ks * 32;
        const int g  = kk >> 8;
        const int il = kk & 255;
        int gp = g - h; if (gp < 0) gp += NG;
        const uint4* pa = (const uint4*)(Ap + kk);
        uint4 a0 = pa[0], a1 = pa[1], a2 = pa[2], a3 = pa[3];
        uint4 b0, b1, b2, b3;
        if (tid < 128) {
            const uint4* pb = (const uint4*)(Wp + ((size_t)gp * 64 + brow) * 256 + il);
            b0 = pb[0]; b1 = pb[1]; b2 = pb[2]; b3 = pb[3];
        }
        __syncthreads();
        *(uint4*)&As[spl][srow][0]  = a0;
        *(uint4*)&As[spl][srow][8]  = a1;
        *(uint4*)&As[spl][srow][16] = a2;
        *(uint4*)&As[spl][srow][24] = a3;
        if (tid < 128) {
            *(uint4*)&Bs[bpl][brow][0]  = b0;
            *(uint4*)&Bs[bpl][brow][8]  = b1;
            *(uint4*)&Bs[bpl][brow][16] = b2;
            *(uint4*)&Bs[bpl][brow][24] = b3;
        }
        __syncthreads();

        bf16x8 ah[4], al[4], bh[2], bl[2];
        #pragma unroll
        for (int t = 0; t < 4; ++t) {
            ah[t] = *(const bf16x8*)&As[0][wm + t * 16 + lm][lq * 8];
            al[t] = *(const bf16x8*)&As[1][wm + t * 16 + lm][lq * 8];
        }
        #pragma unroll
        for (int t = 0; t < 2; ++t) {
            bh[t] = *(const bf16x8*)&Bs[0][wn + t * 16 + lm][lq * 8];
            bl[t] = *(const bf16x8*)&Bs[1][wn + t * 16 + lm][lq * 8];
        }
        #pragma unroll
        for (int mt = 0; mt < 4; ++mt)
            #pragma unroll
            for (int nt = 0; nt < 2; ++nt) {
                acc[mt][nt] = __builtin_amdgcn_mfma_f32_16x16x32_bf16(ah[mt], bh[nt], acc[mt][nt], 0, 0, 0);
                acc[mt][nt] = __builtin_amdgcn_mfma_f32_16x16x32_bf16(ah[mt], bl[nt], acc[mt][nt], 0, 0, 0);
                acc[mt][nt] = __builtin_amdgcn_mfma_f32_16x16x32_bf16(al[mt], bh[nt], acc[mt][nt], 0, 0, 0);
            }
    }
    float* dst0 = part + (size_t)kz * (NROWS * DOUT);
    #pragma unroll
    for (int mt = 0; mt < 4; ++mt)
        #pragma unroll
        for (int r = 0; r < 4; ++r) {
            float* dst = dst0 + (size_t)(m0 + wm + mt * 16 + lq * 4 + r) * DOUT + h * 64 + wn + lm;
            dst[0]  = acc[mt][0][r];
            dst[16] = acc[mt][1][r];
        }
}

__global__ __launch_bounds__(256) void reduce8_kernel(
    const float* __restrict__ part, float* __restrict__ out)
{
    const int i = blockIdx.x * 256 + threadIdx.x;   // over 196608 float4s
    const float4* p = (const float4*)part;
    const int s = NROWS * DOUT / 4;                 // 196608
    float4 r = p[i];
    #pragma unroll
    for (int j = 1; j < 8; ++j) {
        float4 t = p[i + j * s];
        r.x += t.x; r.y += t.y; r.z += t.z; r.w += t.w;
    }
    ((float4*)out)[i] = r;
}

// ---------------------------------------------------------------------------
extern "C" void kernel_launch(void* const* d_in, const int* in_sizes, int n_in,
                              void* d_out, int out_size, void* d_ws, size_t ws_size,
                              hipStream_t stream)
{
    const float* feat   = (const float*)d_in[0];
    const float* coords = (const float*)d_in[1];
    const float* Wq     = (const float*)d_in[2];
    const float* Wk     = (const float*)d_in[3];
    const float* Wv     = (const float*)d_in[4];
    const float* Wo     = (const float*)d_in[5];
    const float* qw     = (const float*)d_in[6];
    const float* kw     = (const float*)d_in[7];
    const float* pf     = (const float*)d_in[8];
    const int*   seq    = (const int*)d_in[9];

    const size_t SZ = (size_t)NROWS * DQK;          // 3145728 floats
    float* q  = (float*)d_ws;
    float* k  = q + SZ;
    float* v  = k + SZ;
    float* ao = v + SZ;

    // phase 1: bf16 hi/lo planes for x + swizzled Wqkv in dead ao region
    ushort_t* Xhi  = (ushort_t*)ao;
    ushort_t* Xlo  = Xhi + (size_t)NROWS * DIN;              // 786432
    ushort_t* Wqh  = Xlo + (size_t)NROWS * DIN;
    ushort_t* Wql  = Wqh + (size_t)3 * NG * 256 * 64;        // 589824
    // phase 2: attn writes split AO planes into ao region directly;
    // Wo splits into v region (dead after attn); partials span q+k regions.
    ushort_t* AOhi = (ushort_t*)ao;
    ushort_t* AOlo = AOhi + SZ;                              // SZ ushorts each
    ushort_t* WOhi = (ushort_t*)v;
    ushort_t* WOlo = WOhi + (size_t)NG * COUT * 256;         // 196608
    float*    part = (float*)d_ws;                           // 8 x 786432 floats (q+k regions)

    prep_kernel<<<dim3(1056), 256, 0, stream>>>(feat, Wq, Wk, Wv, Xhi, Xlo, Wqh, Wql);
    qkv_mfma_kernel<<<dim3(48, 8, 3), 256, 0, stream>>>(Xhi, Xlo, Wqh, Wql, q, k, v);
    norm_rope_kernel<<<dim3(384), 256, 0, stream>>>(q, k, coords, seq, qw, kw, pf);
    attn_mfma_kernel<<<dim3(96, 4, 2), 256, 0, stream>>>(q, k, v, AOhi, AOlo);

    split_kernel<<<dim3(192), 256, 0, stream>>>(Wo, WOhi, WOlo, (NG * COUT * 256) / 4);
    oproj_mfma_kernel<<<dim3(12, 8, 8), 256, 0, stream>>>(AOhi, AOlo, WOhi, WOlo, part);
    reduce8_kernel<<<dim3(768), 256, 0, stream>>>(part, (float*)d_out);
}

// Round 9
// 217.009 us; speedup vs baseline: 1.2434x; 1.2434x over previous
//
#include <hip/hip_runtime.h>
#include <math.h>

// Problem constants
#define NG   12
#define NH   8
#define CIN  64
#define CQK  32
#define CVAL 32
#define COUT 64
#define NB   2
#define NN   512
#define NROWS (NB * NN)     // 1024
#define GHH  (NG * NH)      // 96 heads
#define DIN  (NG * CIN)     // 768
#define DQK  (GHH * CQK)    // 3072
#define DOUT (NG * COUT)    // 768

typedef __attribute__((ext_vector_type(8))) short bf16x8;
typedef __attribute__((ext_vector_type(4))) float f32x4;
typedef unsigned short ushort_t;

// ---------------------------------------------------------------------------
// split fp32 -> (hi, lo) bf16 planes.  x = hi + lo + O(2^-16 x).
// ---------------------------------------------------------------------------
__device__ __forceinline__ ushort_t bf16_rne(float v) {
    unsigned u = __float_as_uint(v);
    return (ushort_t)((u + 0x7fffu + ((u >> 16) & 1u)) >> 16);
}

// ---------------------------------------------------------------------------
// Fused prep (block-range dispatch):
// blocks [0,384):   X split + swizzle into A-frag order Xr[m>>4][kc][m&15][8]
// blocks [384,672): Wq/Wk/Wv split + swizzle into B-frag order
//                   Wr[gp][o>>4][kc][o&15][8]  (kc = within-group k>>3)
// A wave's fragment load of either becomes one contiguous 1 KB read.
// ---------------------------------------------------------------------------
__global__ __launch_bounds__(256) void prep_kernel(
    const float* __restrict__ feat,
    const float* __restrict__ Wq, const float* __restrict__ Wk,
    const float* __restrict__ Wv,
    ushort_t* __restrict__ Xrh, ushort_t* __restrict__ Xrl,
    ushort_t* __restrict__ Wqh, ushort_t* __restrict__ Wql)
{
    const int bb = blockIdx.x;
    if (bb < 384) {
        const int t  = bb * 256 + threadIdx.x;   // [0, 98304)
        const int mr  = t & 15;
        const int u   = t >> 4;
        const int kc  = u % 96;
        const int m16 = u / 96;
        const float* src = feat + (size_t)(m16 * 16 + mr) * DIN + kc * 8;
        float v[8];
        *(float4*)v       = *(const float4*)src;
        *(float4*)(v + 4) = *(const float4*)(src + 4);
        ushort_t h8[8] __attribute__((aligned(16)));
        ushort_t l8[8] __attribute__((aligned(16)));
        #pragma unroll
        for (int j = 0; j < 8; ++j) {
            ushort_t hb = bf16_rne(v[j]);
            float hf = __uint_as_float(((unsigned)hb) << 16);
            h8[j] = hb;
            l8[j] = bf16_rne(v[j] - hf);
        }
        const size_t dst = ((size_t)m16 * 96 + kc) * 128 + mr * 8;
        *(uint4*)(Xrh + dst) = *(const uint4*)h8;
        *(uint4*)(Xrl + dst) = *(const uint4*)l8;
    } else {
        const int zz = (bb - 384) / 96;
        const float* W = (zz == 0) ? Wq : (zz == 1) ? Wk : Wv;
        ushort_t* hi = Wqh + (size_t)zz * 196608;
        ushort_t* lo = Wql + (size_t)zz * 196608;
        const int t  = ((bb - 384) % 96) * 256 + threadIdx.x;   // [0, 24576)
        const int kc = t & 7;
        const int o  = (t >> 3) & 255;
        const int gp = t >> 11;
        const float* src = W + ((size_t)(gp * 256 + o)) * 64 + kc * 8;
        float v[8];
        *(float4*)v       = *(const float4*)src;
        *(float4*)(v + 4) = *(const float4*)(src + 4);
        ushort_t h8[8] __attribute__((aligned(16)));
        ushort_t l8[8] __attribute__((aligned(16)));
        #pragma unroll
        for (int j = 0; j < 8; ++j) {
            ushort_t hb = bf16_rne(v[j]);
            float hf = __uint_as_float(((unsigned)hb) << 16);
            h8[j] = hb;
            l8[j] = bf16_rne(v[j] - hf);
        }
        const size_t dst = ((size_t)(gp * 16 + (o >> 4)) * 8 + kc) * 128 + (o & 15) * 8;
        *(uint4*)(hi + dst) = *(const uint4*)h8;
        *(uint4*)(lo + dst) = *(const uint4*)l8;
    }
}

// ---------------------------------------------------------------------------
// Wo split + swizzle (runs after attn; lives in the then-dead v region).
// Wor[gp][o>>4][kc][o&15][8], kc in [0,32) over 256 k.
// ---------------------------------------------------------------------------
__global__ __launch_bounds__(256) void wo_swz_kernel(
    const float* __restrict__ Wo, ushort_t* __restrict__ hi,
    ushort_t* __restrict__ lo)
{
    const int t  = blockIdx.x * 256 + threadIdx.x;   // [0, 24576)
    const int kc = t & 31;
    const int o  = (t >> 5) & 63;
    const int gp = t >> 11;
    const float* src = Wo + ((size_t)(gp * 64 + o)) * 256 + kc * 8;
    float v[8];
    *(float4*)v       = *(const float4*)src;
    *(float4*)(v + 4) = *(const float4*)(src + 4);
    ushort_t h8[8] __attribute__((aligned(16)));
    ushort_t l8[8] __attribute__((aligned(16)));
    #pragma unroll
    for (int j = 0; j < 8; ++j) {
        ushort_t hb = bf16_rne(v[j]);
        float hf = __uint_as_float(((unsigned)hb) << 16);
        h8[j] = hb;
        l8[j] = bf16_rne(v[j] - hf);
    }
    const size_t dst = ((size_t)(gp * 4 + (o >> 4)) * 32 + kc) * 128 + (o & 15) * 8;
    *(uint4*)(hi + dst) = *(const uint4*)h8;
    *(uint4*)(lo + dst) = *(const uint4*)l8;
}

// ---------------------------------------------------------------------------
// Kernel 1: block-circulant QKV projection, split-bf16 MFMA, NO LDS/barriers.
// 128x128 tile, wave 64x64. A and B both stream from global in fragment
// order (coalesced 1 KB wave reads, L2-served). 48 MFMAs per k-step.
// ---------------------------------------------------------------------------
__global__ __launch_bounds__(256, 1) void qkv_mfma_kernel(
    const ushort_t* __restrict__ Xrh, const ushort_t* __restrict__ Xrl,
    const ushort_t* __restrict__ Wrh, const ushort_t* __restrict__ Wrl,
    float* __restrict__ qo, float* __restrict__ ko, float* __restrict__ vo)
{
    const int z = blockIdx.z;
    float* __restrict__ out = (z == 0) ? qo : (z == 1) ? ko : vo;
    const ushort_t* Wh = Wrh + (size_t)z * 196608;
    const ushort_t* Wl = Wrl + (size_t)z * 196608;
    const int m0 = blockIdx.y * 128;
    const int c0 = blockIdx.x * 128;
    const int hg = c0 >> 8;
    const int o0 = c0 & 255;
    const int tid  = threadIdx.x;
    const int lane = tid & 63;
    const int w    = tid >> 6;
    const int wm   = (w >> 1) * 64;
    const int wn   = (w & 1) * 64;
    const int lm   = lane & 15;
    const int lq   = lane >> 4;
    const int tA0  = (m0 + wm) >> 4;        // A m-tile base
    const int ct0  = (o0 + wn) >> 4;        // B col-tile base

    f32x4 acc[4][4];
    #pragma unroll
    for (int i = 0; i < 4; ++i)
        #pragma unroll
        for (int j = 0; j < 4; ++j) acc[i][j] = (f32x4)(0.0f);

    for (int ks = 0; ks < 24; ++ks) {
        const int g = ks >> 1;
        int gp = g - hg; if (gp < 0) gp += NG;
        // ---- A fragments (global, frag order) ----
        bf16x8 ah[4], al[4], bh[4], bl[4];
        #pragma unroll
        for (int mt = 0; mt < 4; ++mt) {
            const size_t aoff = ((size_t)(tA0 + mt) * 96 + ks * 4 + lq) * 128 + lm * 8;
            ah[mt] = *(const bf16x8*)(Xrh + aoff);
            al[mt] = *(const bf16x8*)(Xrl + aoff);
        }
        // ---- B fragments (global, frag order) ----
        const size_t bbase = ((size_t)(gp * 16 + ct0) * 8 + (ks & 1) * 4 + lq) * 128 + lm * 8;
        #pragma unroll
        for (int nt = 0; nt < 4; ++nt) {
            bh[nt] = *(const bf16x8*)(Wh + bbase + nt * 1024);
            bl[nt] = *(const bf16x8*)(Wl + bbase + nt * 1024);
        }
        #pragma unroll
        for (int mt = 0; mt < 4; ++mt)
            #pragma unroll
            for (int nt = 0; nt < 4; ++nt) {
                acc[mt][nt] = __builtin_amdgcn_mfma_f32_16x16x32_bf16(ah[mt], bh[nt], acc[mt][nt], 0, 0, 0);
                acc[mt][nt] = __builtin_amdgcn_mfma_f32_16x16x32_bf16(ah[mt], bl[nt], acc[mt][nt], 0, 0, 0);
                acc[mt][nt] = __builtin_amdgcn_mfma_f32_16x16x32_bf16(al[mt], bh[nt], acc[mt][nt], 0, 0, 0);
            }
    }
    #pragma unroll
    for (int mt = 0; mt < 4; ++mt)
        #pragma unroll
        for (int r = 0; r < 4; ++r) {
            float* dst = out + (size_t)(m0 + wm + mt * 16 + lq * 4 + r) * DQK + c0 + wn + lm;
            #pragma unroll
            for (int nt = 0; nt < 4; ++nt) dst[nt * 16] = acc[mt][nt][r];
        }
}

// ---------------------------------------------------------------------------
// Kernel 2: RMSNorm + fused sequence-rope + platonic-rope (unchanged).
// ---------------------------------------------------------------------------
__global__ __launch_bounds__(256) void norm_rope_kernel(
    float* __restrict__ q, float* __restrict__ k,
    const float* __restrict__ coords,
    const int* __restrict__ seq,
    const float* __restrict__ qw,
    const float* __restrict__ kw,
    const float* __restrict__ pf)
{
    const int hid = blockIdx.x * 256 + threadIdx.x;
    const int gh = hid % GHH;
    const int bn = hid / GHH;
    const int g = gh >> 3;
    const int h = gh & 7;
    float* qp = q + (size_t)hid * CQK;
    float* kp = k + (size_t)hid * CQK;
    float xq[CQK], xk[CQK];
    #pragma unroll
    for (int u = 0; u < 8; ++u) *(float4*)(xq + 4 * u) = *(const float4*)(qp + 4 * u);
    #pragma unroll
    for (int u = 0; u < 8; ++u) *(float4*)(xk + 4 * u) = *(const float4*)(kp + 4 * u);

    float sq = 0.f, sk = 0.f;
    #pragma unroll
    for (int c = 0; c < CQK; ++c) { sq = fmaf(xq[c], xq[c], sq); sk = fmaf(xk[c], xk[c], sk); }
    const float eps = 1.1920928955078125e-07f;
    const float invq = rsqrtf(sq * (1.f / CQK) + eps);
    const float invk = rsqrtf(sk * (1.f / CQK) + eps);
    #pragma unroll
    for (int c = 0; c < CQK; ++c) { xq[c] *= invq * qw[c]; xk[c] *= invk * kw[c]; }

    const float pos = (float)seq[bn];
    const float cx = coords[bn * 3 + 0], cy = coords[bn * 3 + 1], cz = coords[bn * 3 + 2];
    float sg, cg;
    sincosf((float)g * 0.5235987755982988f, &sg, &cg);
    const float u0 = cg * cx + sg * cy;
    const float u1 = cg * cy - sg * cx;
    const float u2 = cz;

    #pragma unroll
    for (int f = 0; f < 16; ++f) {
        const float invf = exp2f(-(float)f * 0.8304820237218405f);
        const float* fr = pf + ((size_t)h * 16 + f) * 3;
        const float ang = fmaf(pos, invf, u0 * fr[0] + u1 * fr[1] + u2 * fr[2]);
        float sn, cs;
        sincosf(ang, &sn, &cs);
        float a1 = xq[2 * f], a2 = xq[2 * f + 1];
        xq[2 * f]     = a1 * cs - a2 * sn;
        xq[2 * f + 1] = a1 * sn + a2 * cs;
        float b1 = xk[2 * f], b2 = xk[2 * f + 1];
        xk[2 * f]     = b1 * cs - b2 * sn;
        xk[2 * f + 1] = b1 * sn + b2 * cs;
    }
    #pragma unroll
    for (int u = 0; u < 8; ++u) *(float4*)(qp + 4 * u) = *(const float4*)(xq + 4 * u);
    #pragma unroll
    for (int u = 0; u < 8; ++u) *(float4*)(kp + 4 * u) = *(const float4*)(xk + 4 * u);
}

// ---------------------------------------------------------------------------
// Kernel 3: MFMA flash attention. Epilogue writes AO split planes directly
// in A-FRAGMENT order (so oproj needs no LDS).
// ---------------------------------------------------------------------------
__global__ __launch_bounds__(256, 1) void attn_mfma_kernel(
    const float* __restrict__ q,
    const float* __restrict__ k,
    const float* __restrict__ v,
    ushort_t* __restrict__ aoh,     // A-frag order [m>>4][384][16][8]
    ushort_t* __restrict__ aol)
{
    __shared__ __attribute__((aligned(16))) ushort_t Kh[128][40];
    __shared__ __attribute__((aligned(16))) ushort_t Kl[128][40];
    __shared__ __attribute__((aligned(16))) ushort_t Vth[32][136];
    __shared__ __attribute__((aligned(16))) ushort_t Vtl[32][136];
    __shared__ __attribute__((aligned(16))) ushort_t Ps[128][136];

    const int gh    = blockIdx.x;
    const int chunk = blockIdx.y;
    const int b     = blockIdx.z;
    const size_t headoff = (size_t)b * NN * DQK + (size_t)gh * CQK;
    const int tid  = threadIdx.x;
    const int lane = tid & 63;
    const int w    = tid >> 6;
    const int lm   = lane & 15;
    const int lq   = lane >> 4;       // quad
    const int qloc = w * 32;          // wave's local q-row base (0..96)

    const float scale = 0.17677669529663687f;  // 1/sqrt(32)
    bf16x8 qh[2], ql[2];
    #pragma unroll
    for (int mt = 0; mt < 2; ++mt) {
        const int row = chunk * 128 + qloc + mt * 16 + lm;
        const float* qp = q + headoff + (size_t)row * DQK + lq * 8;
        float4 t0 = *(const float4*)qp;
        float4 t1 = *(const float4*)(qp + 4);
        float vals[8] = {t0.x, t0.y, t0.z, t0.w, t1.x, t1.y, t1.z, t1.w};
        short h8[8], l8[8];
        #pragma unroll
        for (int j = 0; j < 8; ++j) {
            float x = vals[j] * scale;
            ushort_t hb = bf16_rne(x);
            float hf = __uint_as_float(((unsigned)hb) << 16);
            h8[j] = (short)hb;
            l8[j] = (short)bf16_rne(x - hf);
        }
        qh[mt] = *(bf16x8*)h8;
        ql[mt] = *(bf16x8*)l8;
    }

    float mrun[2][4], lrun[2][4];
    f32x4 o[2][2];
    #pragma unroll
    for (int mt = 0; mt < 2; ++mt) {
        #pragma unroll
        for (int r = 0; r < 4; ++r) { mrun[mt][r] = -3.0e38f; lrun[mt][r] = 0.f; }
        o[mt][0] = (f32x4)(0.0f); o[mt][1] = (f32x4)(0.0f);
    }

    const int sr = tid >> 1;          // staging row 0..127
    const int sh = (tid & 1) * 16;    // staging col half

    for (int j0 = 0; j0 < NN; j0 += 128) {
        const float* kp = k + headoff + (size_t)(j0 + sr) * DQK + sh;
        const float* vp = v + headoff + (size_t)(j0 + sr) * DQK + sh;
        float kb[16], vb[16];
        #pragma unroll
        for (int u = 0; u < 4; ++u) *(float4*)(kb + 4 * u) = *(const float4*)(kp + 4 * u);
        #pragma unroll
        for (int u = 0; u < 4; ++u) *(float4*)(vb + 4 * u) = *(const float4*)(vp + 4 * u);
        __syncthreads();   // previous iteration's PV reads done
        ushort_t kh16[16] __attribute__((aligned(16)));
        ushort_t kl16[16] __attribute__((aligned(16)));
        #pragma unroll
        for (int i = 0; i < 16; ++i) {
            ushort_t hb = bf16_rne(kb[i]);
            float hf = __uint_as_float(((unsigned)hb) << 16);
            kh16[i] = hb;
            kl16[i] = bf16_rne(kb[i] - hf);
            ushort_t vh = bf16_rne(vb[i]);
            float vf = __uint_as_float(((unsigned)vh) << 16);
            Vth[sh + i][sr] = vh;
            Vtl[sh + i][sr] = bf16_rne(vb[i] - vf);
        }
        *(uint4*)&Kh[sr][sh]     = *(uint4*)&kh16[0];
        *(uint4*)&Kh[sr][sh + 8] = *(uint4*)&kh16[8];
        *(uint4*)&Kl[sr][sh]     = *(uint4*)&kl16[0];
        *(uint4*)&Kl[sr][sh + 8] = *(uint4*)&kl16[8];
        __syncthreads();

        f32x4 sf[2][8];
        #pragma unroll
        for (int nt = 0; nt < 8; ++nt) {
            bf16x8 bh = *(const bf16x8*)&Kh[nt * 16 + lm][lq * 8];
            bf16x8 bl = *(const bf16x8*)&Kl[nt * 16 + lm][lq * 8];
            #pragma unroll
            for (int mt = 0; mt < 2; ++mt) {
                f32x4 s = (f32x4)(0.0f);
                s = __builtin_amdgcn_mfma_f32_16x16x32_bf16(qh[mt], bh, s, 0, 0, 0);
                s = __builtin_amdgcn_mfma_f32_16x16x32_bf16(qh[mt], bl, s, 0, 0, 0);
                s = __builtin_amdgcn_mfma_f32_16x16x32_bf16(ql[mt], bh, s, 0, 0, 0);
                sf[mt][nt] = s;
            }
        }

        #pragma unroll
        for (int mt = 0; mt < 2; ++mt) {
            float cr[4];
            #pragma unroll
            for (int r = 0; r < 4; ++r) {
                float t = sf[mt][0][r];
                #pragma unroll
                for (int nt = 1; nt < 8; ++nt) t = fmaxf(t, sf[mt][nt][r]);
                t = fmaxf(t, __shfl_xor(t, 1, 64));
                t = fmaxf(t, __shfl_xor(t, 2, 64));
                t = fmaxf(t, __shfl_xor(t, 4, 64));
                t = fmaxf(t, __shfl_xor(t, 8, 64));
                const float mn = fmaxf(mrun[mt][r], t);
                cr[r] = __expf(mrun[mt][r] - mn);
                mrun[mt][r] = mn;
                lrun[mt][r] *= cr[r];
            }
            o[mt][0] *= f32x4{cr[0], cr[1], cr[2], cr[3]};
            o[mt][1] *= f32x4{cr[0], cr[1], cr[2], cr[3]};
            float rsum[4] = {0.f, 0.f, 0.f, 0.f};
            #pragma unroll
            for (int nt = 0; nt < 8; ++nt) {
                #pragma unroll
                for (int r = 0; r < 4; ++r) {
                    const float p = __expf(sf[mt][nt][r] - mrun[mt][r]);
                    rsum[r] += p;
                    Ps[qloc + mt * 16 + lq * 4 + r][nt * 16 + lm] = bf16_rne(p);
                }
            }
            #pragma unroll
            for (int r = 0; r < 4; ++r) {
                float t = rsum[r];
                t += __shfl_xor(t, 1, 64);
                t += __shfl_xor(t, 2, 64);
                t += __shfl_xor(t, 4, 64);
                t += __shfl_xor(t, 8, 64);
                lrun[mt][r] += t;
            }
        }
        __syncthreads();

        #pragma unroll
        for (int kt = 0; kt < 4; ++kt) {
            bf16x8 pa[2];
            #pragma unroll
            for (int mt = 0; mt < 2; ++mt)
                pa[mt] = *(const bf16x8*)&Ps[qloc + mt * 16 + lm][kt * 32 + lq * 8];
            #pragma unroll
            for (int vt = 0; vt < 2; ++vt) {
                bf16x8 bvh = *(const bf16x8*)&Vth[vt * 16 + lm][kt * 32 + lq * 8];
                bf16x8 bvl = *(const bf16x8*)&Vtl[vt * 16 + lm][kt * 32 + lq * 8];
                #pragma unroll
                for (int mt = 0; mt < 2; ++mt) {
                    o[mt][vt] = __builtin_amdgcn_mfma_f32_16x16x32_bf16(pa[mt], bvh, o[mt][vt], 0, 0, 0);
                    o[mt][vt] = __builtin_amdgcn_mfma_f32_16x16x32_bf16(pa[mt], bvl, o[mt][vt], 0, 0, 0);
                }
            }
        }
    }

    // ---- epilogue: normalize + split-bf16 store in A-FRAGMENT order ----
    // m_global = b*512 + chunk*128 + qloc + mt*16 + (lq*4+r)
    // col0 = gh*32+lm -> kc0 = gh*4+(lm>>3), j = lm&7; col1 = col0+16 -> kc0+2
    const int mtbase = (b * 512 + chunk * 128 + qloc) >> 4;
    const int kc0 = gh * 4 + (lm >> 3);
    const int j0w = lm & 7;
    #pragma unroll
    for (int mt = 0; mt < 2; ++mt) {
        float inv[4];
        #pragma unroll
        for (int r = 0; r < 4; ++r) inv[r] = 1.f / lrun[mt][r];
        #pragma unroll
        for (int r = 0; r < 4; ++r) {
            const size_t base = ((size_t)(mtbase + mt) * 384 + kc0) * 128 + (lq * 4 + r) * 8 + j0w;
            const float x0 = o[mt][0][r] * inv[r];
            const float x1 = o[mt][1][r] * inv[r];
            const ushort_t h0 = bf16_rne(x0);
            const ushort_t h1 = bf16_rne(x1);
            aoh[base]       = h0;
            aoh[base + 256] = h1;   // +2 kc
            aol[base]       = bf16_rne(x0 - __uint_as_float(((unsigned)h0) << 16));
            aol[base + 256] = bf16_rne(x1 - __uint_as_float(((unsigned)h1) << 16));
        }
    }
}

// ---------------------------------------------------------------------------
// Kernel 4: output projection, split-bf16 MFMA, split-K=8, NO LDS/barriers.
// Block 128m x 64n (wave 64x32). A from AO frag planes, B from Wor planes.
// ---------------------------------------------------------------------------
__global__ __launch_bounds__(256, 1) void oproj_mfma_kernel(
    const ushort_t* __restrict__ Arh, const ushort_t* __restrict__ Arl,
    const ushort_t* __restrict__ Worh, const ushort_t* __restrict__ Worl,
    float* __restrict__ part)                                 // [8][1024][768]
{
    const int h  = blockIdx.x;
    const int m0 = blockIdx.y * 128;
    const int kz = blockIdx.z;
    const int tid  = threadIdx.x;
    const int lane = tid & 63;
    const int w    = tid >> 6;
    const int wm   = (w >> 1) * 64;
    const int wn   = (w & 1) * 32;
    const int lm   = lane & 15;
    const int lq   = lane >> 4;
    const int tA0  = (m0 + wm) >> 4;
    const int ctb  = wn >> 4;               // 0 or 2

    f32x4 acc[4][2];
    #pragma unroll
    for (int i = 0; i < 4; ++i) { acc[i][0] = (f32x4)(0.0f); acc[i][1] = (f32x4)(0.0f); }

    for (int ks = 0; ks < 12; ++ks) {
        const int k0 = kz * 384 + ks * 32;
        const int g  = k0 >> 8;
        int gp = g - h; if (gp < 0) gp += NG;
        const int kcA = kz * 48 + ks * 4 + lq;          // global k-chunk 0..383
        const int kcB = ((k0 & 255) >> 3) + lq;         // within-group 0..31
        bf16x8 ah[4], al[4], bh[2], bl[2];
        #pragma unroll
        for (int mt = 0; mt < 4; ++mt) {
            const size_t aoff = ((size_t)(tA0 + mt) * 384 + kcA) * 128 + lm * 8;
            ah[mt] = *(const bf16x8*)(Arh + aoff);
            al[mt] = *(const bf16x8*)(Arl + aoff);
        }
        const size_t bbase = ((size_t)(gp * 4 + ctb) * 32 + kcB) * 128 + lm * 8;
        #pragma unroll
        for (int nt = 0; nt < 2; ++nt) {
            bh[nt] = *(const bf16x8*)(Worh + bbase + nt * 4096);
            bl[nt] = *(const bf16x8*)(Worl + bbase + nt * 4096);
        }
        #pragma unroll
        for (int mt = 0; mt < 4; ++mt)
            #pragma unroll
            for (int nt = 0; nt < 2; ++nt) {
                acc[mt][nt] = __builtin_amdgcn_mfma_f32_16x16x32_bf16(ah[mt], bh[nt], acc[mt][nt], 0, 0, 0);
                acc[mt][nt] = __builtin_amdgcn_mfma_f32_16x16x32_bf16(ah[mt], bl[nt], acc[mt][nt], 0, 0, 0);
                acc[mt][nt] = __builtin_amdgcn_mfma_f32_16x16x32_bf16(al[mt], bh[nt], acc[mt][nt], 0, 0, 0);
            }
    }
    float* dst0 = part + (size_t)kz * (NROWS * DOUT);
    #pragma unroll
    for (int mt = 0; mt < 4; ++mt)
        #pragma unroll
        for (int r = 0; r < 4; ++r) {
            float* dst = dst0 + (size_t)(m0 + wm + mt * 16 + lq * 4 + r) * DOUT + h * 64 + wn + lm;
            dst[0]  = acc[mt][0][r];
            dst[16] = acc[mt][1][r];
        }
}

__global__ __launch_bounds__(256) void reduce8_kernel(
    const float* __restrict__ part, float* __restrict__ out)
{
    const int i = blockIdx.x * 256 + threadIdx.x;   // over 196608 float4s
    const float4* p = (const float4*)part;
    const int s = NROWS * DOUT / 4;                 // 196608
    float4 r = p[i];
    #pragma unroll
    for (int j = 1; j < 8; ++j) {
        float4 t = p[i + j * s];
        r.x += t.x; r.y += t.y; r.z += t.z; r.w += t.w;
    }
    ((float4*)out)[i] = r;
}

// ---------------------------------------------------------------------------
extern "C" void kernel_launch(void* const* d_in, const int* in_sizes, int n_in,
                              void* d_out, int out_size, void* d_ws, size_t ws_size,
                              hipStream_t stream)
{
    const float* feat   = (const float*)d_in[0];
    const float* coords = (const float*)d_in[1];
    const float* Wq     = (const float*)d_in[2];
    const float* Wk     = (const float*)d_in[3];
    const float* Wv     = (const float*)d_in[4];
    const float* Wo     = (const float*)d_in[5];
    const float* qw     = (const float*)d_in[6];
    const float* kw     = (const float*)d_in[7];
    const float* pf     = (const float*)d_in[8];
    const int*   seq    = (const int*)d_in[9];

    const size_t SZ = (size_t)NROWS * DQK;          // 3145728 floats
    float* q  = (float*)d_ws;
    float* k  = q + SZ;
    float* v  = k + SZ;
    float* ao = v + SZ;

    // phase 1: X frag planes + swizzled Wqkv in the dead ao region
    ushort_t* Xrh = (ushort_t*)ao;
    ushort_t* Xrl = Xrh + (size_t)NROWS * DIN;               // 786432 each
    ushort_t* Wqh = Xrl + (size_t)NROWS * DIN;
    ushort_t* Wql = Wqh + (size_t)3 * 196608;
    // phase 2: attn writes AO frag planes over the ao region;
    // Wo swizzles into the then-dead v region; partials span q+k regions.
    ushort_t* AOrh = (ushort_t*)ao;
    ushort_t* AOrl = AOrh + SZ;                              // SZ ushorts each
    ushort_t* WOrh = (ushort_t*)v;
    ushort_t* WOrl = WOrh + (size_t)196608;
    float*    part = (float*)d_ws;                           // 8 x 786432 floats

    prep_kernel<<<dim3(672), 256, 0, stream>>>(feat, Wq, Wk, Wv, Xrh, Xrl, Wqh, Wql);
    qkv_mfma_kernel<<<dim3(24, 8, 3), 256, 0, stream>>>(Xrh, Xrl, Wqh, Wql, q, k, v);
    norm_rope_kernel<<<dim3(384), 256, 0, stream>>>(q, k, coords, seq, qw, kw, pf);
    attn_mfma_kernel<<<dim3(96, 4, 2), 256, 0, stream>>>(q, k, v, AOrh, AOrl);

    wo_swz_kernel<<<dim3(96), 256, 0, stream>>>(Wo, WOrh, WOrl);
    oproj_mfma_kernel<<<dim3(12, 8, 8), 256, 0, stream>>>(AOrh, AOrl, WOrh, WOrl, part);
    reduce8_kernel<<<dim3(768), 256, 0, stream>>>(part, (float*)d_out);
}

// Round 10
// 216.428 us; speedup vs baseline: 1.2468x; 1.0027x over previous
//
#include <hip/hip_runtime.h>
#include <math.h>

// Problem constants
#define NG   12
#define NH   8
#define CIN  64
#define CQK  32
#define CVAL 32
#define COUT 64
#define NB   2
#define NN   512
#define NROWS (NB * NN)     // 1024
#define GHH  (NG * NH)      // 96 heads
#define DIN  (NG * CIN)     // 768
#define DQK  (GHH * CQK)    // 3072
#define DOUT (NG * COUT)    // 768

typedef __attribute__((ext_vector_type(8))) short bf16x8;
typedef __attribute__((ext_vector_type(4))) float f32x4;
typedef unsigned short ushort_t;

// ---------------------------------------------------------------------------
// split fp32 -> (hi, lo) bf16 planes.  x = hi + lo + O(2^-16 x).
// ---------------------------------------------------------------------------
__device__ __forceinline__ ushort_t bf16_rne(float v) {
    unsigned u = __float_as_uint(v);
    return (ushort_t)((u + 0x7fffu + ((u >> 16) & 1u)) >> 16);
}

// ---------------------------------------------------------------------------
// Fused prep (block-range dispatch):
// blocks [0,384):   X split + swizzle into A-frag order Xr[m>>4][kc][m&15][8]
// blocks [384,672): Wq/Wk/Wv split + swizzle into B-frag order
//                   Wr[gp][o>>4][kc][o&15][8]  (kc = within-group k>>3)
// ---------------------------------------------------------------------------
__global__ __launch_bounds__(256) void prep_kernel(
    const float* __restrict__ feat,
    const float* __restrict__ Wq, const float* __restrict__ Wk,
    const float* __restrict__ Wv,
    ushort_t* __restrict__ Xrh, ushort_t* __restrict__ Xrl,
    ushort_t* __restrict__ Wqh, ushort_t* __restrict__ Wql)
{
    const int bb = blockIdx.x;
    if (bb < 384) {
        const int t  = bb * 256 + threadIdx.x;   // [0, 98304)
        const int mr  = t & 15;
        const int u   = t >> 4;
        const int kc  = u % 96;
        const int m16 = u / 96;
        const float* src = feat + (size_t)(m16 * 16 + mr) * DIN + kc * 8;
        float v[8];
        *(float4*)v       = *(const float4*)src;
        *(float4*)(v + 4) = *(const float4*)(src + 4);
        ushort_t h8[8] __attribute__((aligned(16)));
        ushort_t l8[8] __attribute__((aligned(16)));
        #pragma unroll
        for (int j = 0; j < 8; ++j) {
            ushort_t hb = bf16_rne(v[j]);
            float hf = __uint_as_float(((unsigned)hb) << 16);
            h8[j] = hb;
            l8[j] = bf16_rne(v[j] - hf);
        }
        const size_t dst = ((size_t)m16 * 96 + kc) * 128 + mr * 8;
        *(uint4*)(Xrh + dst) = *(const uint4*)h8;
        *(uint4*)(Xrl + dst) = *(const uint4*)l8;
    } else {
        const int zz = (bb - 384) / 96;
        const float* W = (zz == 0) ? Wq : (zz == 1) ? Wk : Wv;
        ushort_t* hi = Wqh + (size_t)zz * 196608;
        ushort_t* lo = Wql + (size_t)zz * 196608;
        const int t  = ((bb - 384) % 96) * 256 + threadIdx.x;   // [0, 24576)
        const int kc = t & 7;
        const int o  = (t >> 3) & 255;
        const int gp = t >> 11;
        const float* src = W + ((size_t)(gp * 256 + o)) * 64 + kc * 8;
        float v[8];
        *(float4*)v       = *(const float4*)src;
        *(float4*)(v + 4) = *(const float4*)(src + 4);
        ushort_t h8[8] __attribute__((aligned(16)));
        ushort_t l8[8] __attribute__((aligned(16)));
        #pragma unroll
        for (int j = 0; j < 8; ++j) {
            ushort_t hb = bf16_rne(v[j]);
            float hf = __uint_as_float(((unsigned)hb) << 16);
            h8[j] = hb;
            l8[j] = bf16_rne(v[j] - hf);
        }
        const size_t dst = ((size_t)(gp * 16 + (o >> 4)) * 8 + kc) * 128 + (o & 15) * 8;
        *(uint4*)(hi + dst) = *(const uint4*)h8;
        *(uint4*)(lo + dst) = *(const uint4*)l8;
    }
}

// ---------------------------------------------------------------------------
// Wo split + swizzle (runs after attn; lives in the then-dead v region).
// Wor[gp][o>>4][kc][o&15][8], kc in [0,32) over 256 k.
// ---------------------------------------------------------------------------
__global__ __launch_bounds__(256) void wo_swz_kernel(
    const float* __restrict__ Wo, ushort_t* __restrict__ hi,
    ushort_t* __restrict__ lo)
{
    const int t  = blockIdx.x * 256 + threadIdx.x;   // [0, 24576)
    const int kc = t & 31;
    const int o  = (t >> 5) & 63;
    const int gp = t >> 11;
    const float* src = Wo + ((size_t)(gp * 64 + o)) * 256 + kc * 8;
    float v[8];
    *(float4*)v       = *(const float4*)src;
    *(float4*)(v + 4) = *(const float4*)(src + 4);
    ushort_t h8[8] __attribute__((aligned(16)));
    ushort_t l8[8] __attribute__((aligned(16)));
    #pragma unroll
    for (int j = 0; j < 8; ++j) {
        ushort_t hb = bf16_rne(v[j]);
        float hf = __uint_as_float(((unsigned)hb) << 16);
        h8[j] = hb;
        l8[j] = bf16_rne(v[j] - hf);
    }
    const size_t dst = ((size_t)(gp * 4 + (o >> 4)) * 32 + kc) * 128 + (o & 15) * 8;
    *(uint4*)(hi + dst) = *(const uint4*)h8;
    *(uint4*)(lo + dst) = *(const uint4*)l8;
}

// ---------------------------------------------------------------------------
// Kernel 1: block-circulant QKV projection, split-bf16 MFMA, NO LDS/barriers.
// ---------------------------------------------------------------------------
__global__ __launch_bounds__(256, 1) void qkv_mfma_kernel(
    const ushort_t* __restrict__ Xrh, const ushort_t* __restrict__ Xrl,
    const ushort_t* __restrict__ Wrh, const ushort_t* __restrict__ Wrl,
    float* __restrict__ qo, float* __restrict__ ko, float* __restrict__ vo)
{
    const int z = blockIdx.z;
    float* __restrict__ out = (z == 0) ? qo : (z == 1) ? ko : vo;
    const ushort_t* Wh = Wrh + (size_t)z * 196608;
    const ushort_t* Wl = Wrl + (size_t)z * 196608;
    const int m0 = blockIdx.y * 128;
    const int c0 = blockIdx.x * 128;
    const int hg = c0 >> 8;
    const int o0 = c0 & 255;
    const int tid  = threadIdx.x;
    const int lane = tid & 63;
    const int w    = tid >> 6;
    const int wm   = (w >> 1) * 64;
    const int wn   = (w & 1) * 64;
    const int lm   = lane & 15;
    const int lq   = lane >> 4;
    const int tA0  = (m0 + wm) >> 4;
    const int ct0  = (o0 + wn) >> 4;

    f32x4 acc[4][4];
    #pragma unroll
    for (int i = 0; i < 4; ++i)
        #pragma unroll
        for (int j = 0; j < 4; ++j) acc[i][j] = (f32x4)(0.0f);

    for (int ks = 0; ks < 24; ++ks) {
        const int g = ks >> 1;
        int gp = g - hg; if (gp < 0) gp += NG;
        bf16x8 ah[4], al[4], bh[4], bl[4];
        #pragma unroll
        for (int mt = 0; mt < 4; ++mt) {
            const size_t aoff = ((size_t)(tA0 + mt) * 96 + ks * 4 + lq) * 128 + lm * 8;
            ah[mt] = *(const bf16x8*)(Xrh + aoff);
            al[mt] = *(const bf16x8*)(Xrl + aoff);
        }
        const size_t bbase = ((size_t)(gp * 16 + ct0) * 8 + (ks & 1) * 4 + lq) * 128 + lm * 8;
        #pragma unroll
        for (int nt = 0; nt < 4; ++nt) {
            bh[nt] = *(const bf16x8*)(Wh + bbase + nt * 1024);
            bl[nt] = *(const bf16x8*)(Wl + bbase + nt * 1024);
        }
        #pragma unroll
        for (int mt = 0; mt < 4; ++mt)
            #pragma unroll
            for (int nt = 0; nt < 4; ++nt) {
                acc[mt][nt] = __builtin_amdgcn_mfma_f32_16x16x32_bf16(ah[mt], bh[nt], acc[mt][nt], 0, 0, 0);
                acc[mt][nt] = __builtin_amdgcn_mfma_f32_16x16x32_bf16(ah[mt], bl[nt], acc[mt][nt], 0, 0, 0);
                acc[mt][nt] = __builtin_amdgcn_mfma_f32_16x16x32_bf16(al[mt], bh[nt], acc[mt][nt], 0, 0, 0);
            }
    }
    #pragma unroll
    for (int mt = 0; mt < 4; ++mt)
        #pragma unroll
        for (int r = 0; r < 4; ++r) {
            float* dst = out + (size_t)(m0 + wm + mt * 16 + lq * 4 + r) * DQK + c0 + wn + lm;
            #pragma unroll
            for (int nt = 0; nt < 4; ++nt) dst[nt * 16] = acc[mt][nt][r];
        }
}

// ---------------------------------------------------------------------------
// Kernel 2: RMSNorm + fused sequence-rope + platonic-rope (unchanged).
// ---------------------------------------------------------------------------
__global__ __launch_bounds__(256) void norm_rope_kernel(
    float* __restrict__ q, float* __restrict__ k,
    const float* __restrict__ coords,
    const int* __restrict__ seq,
    const float* __restrict__ qw,
    const float* __restrict__ kw,
    const float* __restrict__ pf)
{
    const int hid = blockIdx.x * 256 + threadIdx.x;
    const int gh = hid % GHH;
    const int bn = hid / GHH;
    const int g = gh >> 3;
    const int h = gh & 7;
    float* qp = q + (size_t)hid * CQK;
    float* kp = k + (size_t)hid * CQK;
    float xq[CQK], xk[CQK];
    #pragma unroll
    for (int u = 0; u < 8; ++u) *(float4*)(xq + 4 * u) = *(const float4*)(qp + 4 * u);
    #pragma unroll
    for (int u = 0; u < 8; ++u) *(float4*)(xk + 4 * u) = *(const float4*)(kp + 4 * u);

    float sq = 0.f, sk = 0.f;
    #pragma unroll
    for (int c = 0; c < CQK; ++c) { sq = fmaf(xq[c], xq[c], sq); sk = fmaf(xk[c], xk[c], sk); }
    const float eps = 1.1920928955078125e-07f;
    const float invq = rsqrtf(sq * (1.f / CQK) + eps);
    const float invk = rsqrtf(sk * (1.f / CQK) + eps);
    #pragma unroll
    for (int c = 0; c < CQK; ++c) { xq[c] *= invq * qw[c]; xk[c] *= invk * kw[c]; }

    const float pos = (float)seq[bn];
    const float cx = coords[bn * 3 + 0], cy = coords[bn * 3 + 1], cz = coords[bn * 3 + 2];
    float sg, cg;
    sincosf((float)g * 0.5235987755982988f, &sg, &cg);
    const float u0 = cg * cx + sg * cy;
    const float u1 = cg * cy - sg * cx;
    const float u2 = cz;

    #pragma unroll
    for (int f = 0; f < 16; ++f) {
        const float invf = exp2f(-(float)f * 0.8304820237218405f);
        const float* fr = pf + ((size_t)h * 16 + f) * 3;
        const float ang = fmaf(pos, invf, u0 * fr[0] + u1 * fr[1] + u2 * fr[2]);
        float sn, cs;
        sincosf(ang, &sn, &cs);
        float a1 = xq[2 * f], a2 = xq[2 * f + 1];
        xq[2 * f]     = a1 * cs - a2 * sn;
        xq[2 * f + 1] = a1 * sn + a2 * cs;
        float b1 = xk[2 * f], b2 = xk[2 * f + 1];
        xk[2 * f]     = b1 * cs - b2 * sn;
        xk[2 * f + 1] = b1 * sn + b2 * cs;
    }
    #pragma unroll
    for (int u = 0; u < 8; ++u) *(float4*)(qp + 4 * u) = *(const float4*)(xq + 4 * u);
    #pragma unroll
    for (int u = 0; u < 8; ++u) *(float4*)(kp + 4 * u) = *(const float4*)(xk + 4 * u);
}

// ---------------------------------------------------------------------------
// Kernel 3 (RETUNED): MFMA flash attention, K-tile=64.
// LDS 37.9 KB -> 4 blocks/CU -> all 768 blocks co-resident (no tail).
// 2 barriers/iter (the old "Ps visible" barrier was intra-wave -> dropped).
// Epilogue writes AO split planes in A-fragment order.
// ---------------------------------------------------------------------------
__global__ __launch_bounds__(256, 1) void attn_mfma_kernel(
    const float* __restrict__ q,
    const float* __restrict__ k,
    const float* __restrict__ v,
    ushort_t* __restrict__ aoh,     // A-frag order [m>>4][384][16][8]
    ushort_t* __restrict__ aol)
{
    __shared__ __attribute__((aligned(16))) ushort_t Kh[64][40];
    __shared__ __attribute__((aligned(16))) ushort_t Kl[64][40];
    __shared__ __attribute__((aligned(16))) ushort_t Vth[32][72];
    __shared__ __attribute__((aligned(16))) ushort_t Vtl[32][72];
    __shared__ __attribute__((aligned(16))) ushort_t Ps[128][72];

    const int gh    = blockIdx.x;
    const int chunk = blockIdx.y;
    const int b     = blockIdx.z;
    const size_t headoff = (size_t)b * NN * DQK + (size_t)gh * CQK;
    const int tid  = threadIdx.x;
    const int lane = tid & 63;
    const int w    = tid >> 6;
    const int lm   = lane & 15;
    const int lq   = lane >> 4;       // quad
    const int qloc = w * 32;          // wave's local q-row base (0..96)

    const float scale = 0.17677669529663687f;  // 1/sqrt(32)
    bf16x8 qh[2], ql[2];
    #pragma unroll
    for (int mt = 0; mt < 2; ++mt) {
        const int row = chunk * 128 + qloc + mt * 16 + lm;
        const float* qp = q + headoff + (size_t)row * DQK + lq * 8;
        float4 t0 = *(const float4*)qp;
        float4 t1 = *(const float4*)(qp + 4);
        float vals[8] = {t0.x, t0.y, t0.z, t0.w, t1.x, t1.y, t1.z, t1.w};
        short h8[8], l8[8];
        #pragma unroll
        for (int j = 0; j < 8; ++j) {
            float x = vals[j] * scale;
            ushort_t hb = bf16_rne(x);
            float hf = __uint_as_float(((unsigned)hb) << 16);
            h8[j] = (short)hb;
            l8[j] = (short)bf16_rne(x - hf);
        }
        qh[mt] = *(bf16x8*)h8;
        ql[mt] = *(bf16x8*)l8;
    }

    float mrun[2][4], lrun[2][4];
    f32x4 o[2][2];
    #pragma unroll
    for (int mt = 0; mt < 2; ++mt) {
        #pragma unroll
        for (int r = 0; r < 4; ++r) { mrun[mt][r] = -3.0e38f; lrun[mt][r] = 0.f; }
        o[mt][0] = (f32x4)(0.0f); o[mt][1] = (f32x4)(0.0f);
    }

    const int sr = tid >> 2;          // staging row 0..63
    const int sc = (tid & 3) * 8;     // staging col group

    for (int j0 = 0; j0 < NN; j0 += 64) {
        // ---- load + convert K/V tile (64 keys) ----
        const float* kp = k + headoff + (size_t)(j0 + sr) * DQK + sc;
        const float* vp = v + headoff + (size_t)(j0 + sr) * DQK + sc;
        float kb[8], vb[8];
        *(float4*)(kb)     = *(const float4*)(kp);
        *(float4*)(kb + 4) = *(const float4*)(kp + 4);
        *(float4*)(vb)     = *(const float4*)(vp);
        *(float4*)(vb + 4) = *(const float4*)(vp + 4);
        __syncthreads();   // previous iteration's QK/PV reads done
        ushort_t kh8[8] __attribute__((aligned(16)));
        ushort_t kl8[8] __attribute__((aligned(16)));
        #pragma unroll
        for (int i = 0; i < 8; ++i) {
            ushort_t hb = bf16_rne(kb[i]);
            float hf = __uint_as_float(((unsigned)hb) << 16);
            kh8[i] = hb;
            kl8[i] = bf16_rne(kb[i] - hf);
            ushort_t vh = bf16_rne(vb[i]);
            float vf = __uint_as_float(((unsigned)vh) << 16);
            Vth[sc + i][sr] = vh;
            Vtl[sc + i][sr] = bf16_rne(vb[i] - vf);
        }
        *(uint4*)&Kh[sr][sc] = *(uint4*)kh8;
        *(uint4*)&Kl[sr][sc] = *(uint4*)kl8;
        __syncthreads();

        // ---- S = Q K^T for 64 keys (4 n-tiles) ----
        f32x4 sf[2][4];
        #pragma unroll
        for (int nt = 0; nt < 4; ++nt) {
            bf16x8 bh = *(const bf16x8*)&Kh[nt * 16 + lm][lq * 8];
            bf16x8 bl = *(const bf16x8*)&Kl[nt * 16 + lm][lq * 8];
            #pragma unroll
            for (int mt = 0; mt < 2; ++mt) {
                f32x4 s = (f32x4)(0.0f);
                s = __builtin_amdgcn_mfma_f32_16x16x32_bf16(qh[mt], bh, s, 0, 0, 0);
                s = __builtin_amdgcn_mfma_f32_16x16x32_bf16(qh[mt], bl, s, 0, 0, 0);
                s = __builtin_amdgcn_mfma_f32_16x16x32_bf16(ql[mt], bh, s, 0, 0, 0);
                sf[mt][nt] = s;
            }
        }

        // ---- online softmax; P (bf16) -> LDS (wave-private rows) ----
        #pragma unroll
        for (int mt = 0; mt < 2; ++mt) {
            float cr[4];
            #pragma unroll
            for (int r = 0; r < 4; ++r) {
                float t = sf[mt][0][r];
                #pragma unroll
                for (int nt = 1; nt < 4; ++nt) t = fmaxf(t, sf[mt][nt][r]);
                t = fmaxf(t, __shfl_xor(t, 1, 64));
                t = fmaxf(t, __shfl_xor(t, 2, 64));
                t = fmaxf(t, __shfl_xor(t, 4, 64));
                t = fmaxf(t, __shfl_xor(t, 8, 64));
                const float mn = fmaxf(mrun[mt][r], t);
                cr[r] = __expf(mrun[mt][r] - mn);
                mrun[mt][r] = mn;
                lrun[mt][r] *= cr[r];
            }
            o[mt][0] *= f32x4{cr[0], cr[1], cr[2], cr[3]};
            o[mt][1] *= f32x4{cr[0], cr[1], cr[2], cr[3]};
            float rsum[4] = {0.f, 0.f, 0.f, 0.f};
            #pragma unroll
            for (int nt = 0; nt < 4; ++nt) {
                #pragma unroll
                for (int r = 0; r < 4; ++r) {
                    const float p = __expf(sf[mt][nt][r] - mrun[mt][r]);
                    rsum[r] += p;
                    Ps[qloc + mt * 16 + lq * 4 + r][nt * 16 + lm] = bf16_rne(p);
                }
            }
            #pragma unroll
            for (int r = 0; r < 4; ++r) {
                float t = rsum[r];
                t += __shfl_xor(t, 1, 64);
                t += __shfl_xor(t, 2, 64);
                t += __shfl_xor(t, 4, 64);
                t += __shfl_xor(t, 8, 64);
                lrun[mt][r] += t;
            }
        }
        // no barrier: Ps rows are wave-private; Vth staged before barrier 2

        // ---- O += P V (2 k-chunks of 32 keys) ----
        #pragma unroll
        for (int kt = 0; kt < 2; ++kt) {
            bf16x8 pa[2];
            #pragma unroll
            for (int mt = 0; mt < 2; ++mt)
                pa[mt] = *(const bf16x8*)&Ps[qloc + mt * 16 + lm][kt * 32 + lq * 8];
            #pragma unroll
            for (int vt = 0; vt < 2; ++vt) {
                bf16x8 bvh = *(const bf16x8*)&Vth[vt * 16 + lm][kt * 32 + lq * 8];
                bf16x8 bvl = *(const bf16x8*)&Vtl[vt * 16 + lm][kt * 32 + lq * 8];
                #pragma unroll
                for (int mt = 0; mt < 2; ++mt) {
                    o[mt][vt] = __builtin_amdgcn_mfma_f32_16x16x32_bf16(pa[mt], bvh, o[mt][vt], 0, 0, 0);
                    o[mt][vt] = __builtin_amdgcn_mfma_f32_16x16x32_bf16(pa[mt], bvl, o[mt][vt], 0, 0, 0);
                }
            }
        }
    }

    // ---- epilogue: normalize + split-bf16 store in A-FRAGMENT order ----
    const int mtbase = (b * 512 + chunk * 128 + qloc) >> 4;
    const int kc0 = gh * 4 + (lm >> 3);
    const int j0w = lm & 7;
    #pragma unroll
    for (int mt = 0; mt < 2; ++mt) {
        float inv[4];
        #pragma unroll
        for (int r = 0; r < 4; ++r) inv[r] = 1.f / lrun[mt][r];
        #pragma unroll
        for (int r = 0; r < 4; ++r) {
            const size_t base = ((size_t)(mtbase + mt) * 384 + kc0) * 128 + (lq * 4 + r) * 8 + j0w;
            const float x0 = o[mt][0][r] * inv[r];
            const float x1 = o[mt][1][r] * inv[r];
            const ushort_t h0 = bf16_rne(x0);
            const ushort_t h1 = bf16_rne(x1);
            aoh[base]       = h0;
            aoh[base + 256] = h1;   // +2 kc
            aol[base]       = bf16_rne(x0 - __uint_as_float(((unsigned)h0) << 16));
            aol[base + 256] = bf16_rne(x1 - __uint_as_float(((unsigned)h1) << 16));
        }
    }
}

// ---------------------------------------------------------------------------
// Kernel 4: output projection, split-bf16 MFMA, split-K=8, NO LDS/barriers.
// ---------------------------------------------------------------------------
__global__ __launch_bounds__(256, 1) void oproj_mfma_kernel(
    const ushort_t* __restrict__ Arh, const ushort_t* __restrict__ Arl,
    const ushort_t* __restrict__ Worh, const ushort_t* __restrict__ Worl,
    float* __restrict__ part)                                 // [8][1024][768]
{
    const int h  = blockIdx.x;
    const int m0 = blockIdx.y * 128;
    const int kz = blockIdx.z;
    const int tid  = threadIdx.x;
    const int lane = tid & 63;
    const int w    = tid >> 6;
    const int wm   = (w >> 1) * 64;
    const int wn   = (w & 1) * 32;
    const int lm   = lane & 15;
    const int lq   = lane >> 4;
    const int tA0  = (m0 + wm) >> 4;
    const int ctb  = wn >> 4;               // 0 or 2

    f32x4 acc[4][2];
    #pragma unroll
    for (int i = 0; i < 4; ++i) { acc[i][0] = (f32x4)(0.0f); acc[i][1] = (f32x4)(0.0f); }

    for (int ks = 0; ks < 12; ++ks) {
        const int k0 = kz * 384 + ks * 32;
        const int g  = k0 >> 8;
        int gp = g - h; if (gp < 0) gp += NG;
        const int kcA = kz * 48 + ks * 4 + lq;
        const int kcB = ((k0 & 255) >> 3) + lq;
        bf16x8 ah[4], al[4], bh[2], bl[2];
        #pragma unroll
        for (int mt = 0; mt < 4; ++mt) {
            const size_t aoff = ((size_t)(tA0 + mt) * 384 + kcA) * 128 + lm * 8;
            ah[mt] = *(const bf16x8*)(Arh + aoff);
            al[mt] = *(const bf16x8*)(Arl + aoff);
        }
        const size_t bbase = ((size_t)(gp * 4 + ctb) * 32 + kcB) * 128 + lm * 8;
        #pragma unroll
        for (int nt = 0; nt < 2; ++nt) {
            bh[nt] = *(const bf16x8*)(Worh + bbase + nt * 4096);
            bl[nt] = *(const bf16x8*)(Worl + bbase + nt * 4096);
        }
        #pragma unroll
        for (int mt = 0; mt < 4; ++mt)
            #pragma unroll
            for (int nt = 0; nt < 2; ++nt) {
                acc[mt][nt] = __builtin_amdgcn_mfma_f32_16x16x32_bf16(ah[mt], bh[nt], acc[mt][nt], 0, 0, 0);
                acc[mt][nt] = __builtin_amdgcn_mfma_f32_16x16x32_bf16(ah[mt], bl[nt], acc[mt][nt], 0, 0, 0);
                acc[mt][nt] = __builtin_amdgcn_mfma_f32_16x16x32_bf16(al[mt], bh[nt], acc[mt][nt], 0, 0, 0);
            }
    }
    float* dst0 = part + (size_t)kz * (NROWS * DOUT);
    #pragma unroll
    for (int mt = 0; mt < 4; ++mt)
        #pragma unroll
        for (int r = 0; r < 4; ++r) {
            float* dst = dst0 + (size_t)(m0 + wm + mt * 16 + lq * 4 + r) * DOUT + h * 64 + wn + lm;
            dst[0]  = acc[mt][0][r];
            dst[16] = acc[mt][1][r];
        }
}

__global__ __launch_bounds__(256) void reduce8_kernel(
    const float* __restrict__ part, float* __restrict__ out)
{
    const int i = blockIdx.x * 256 + threadIdx.x;   // over 196608 float4s
    const float4* p = (const float4*)part;
    const int s = NROWS * DOUT / 4;                 // 196608
    float4 r = p[i];
    #pragma unroll
    for (int j = 1; j < 8; ++j) {
        float4 t = p[i + j * s];
        r.x += t.x; r.y += t.y; r.z += t.z; r.w += t.w;
    }
    ((float4*)out)[i] = r;
}

// ---------------------------------------------------------------------------
extern "C" void kernel_launch(void* const* d_in, const int* in_sizes, int n_in,
                              void* d_out, int out_size, void* d_ws, size_t ws_size,
                              hipStream_t stream)
{
    const float* feat   = (const float*)d_in[0];
    const float* coords = (const float*)d_in[1];
    const float* Wq     = (const float*)d_in[2];
    const float* Wk     = (const float*)d_in[3];
    const float* Wv     = (const float*)d_in[4];
    const float* Wo     = (const float*)d_in[5];
    const float* qw     = (const float*)d_in[6];
    const float* kw     = (const float*)d_in[7];
    const float* pf     = (const float*)d_in[8];
    const int*   seq    = (const int*)d_in[9];

    const size_t SZ = (size_t)NROWS * DQK;          // 3145728 floats
    float* q  = (float*)d_ws;
    float* k  = q + SZ;
    float* v  = k + SZ;
    float* ao = v + SZ;

    // phase 1: X frag planes + swizzled Wqkv in the dead ao region
    ushort_t* Xrh = (ushort_t*)ao;
    ushort_t* Xrl = Xrh + (size_t)NROWS * DIN;               // 786432 each
    ushort_t* Wqh = Xrl + (size_t)NROWS * DIN;
    ushort_t* Wql = Wqh + (size_t)3 * 196608;
    // phase 2: attn writes AO frag planes over the ao region;
    // Wo swizzles into the then-dead v region; partials span q+k regions.
    ushort_t* AOrh = (ushort_t*)ao;
    ushort_t* AOrl = AOrh + SZ;                              // SZ ushorts each
    ushort_t* WOrh = (ushort_t*)v;
    ushort_t* WOrl = WOrh + (size_t)196608;
    float*    part = (float*)d_ws;                           // 8 x 786432 floats

    prep_kernel<<<dim3(672), 256, 0, stream>>>(feat, Wq, Wk, Wv, Xrh, Xrl, Wqh, Wql);
    qkv_mfma_kernel<<<dim3(24, 8, 3), 256, 0, stream>>>(Xrh, Xrl, Wqh, Wql, q, k, v);
    norm_rope_kernel<<<dim3(384), 256, 0, stream>>>(q, k, coords, seq, qw, kw, pf);
    attn_mfma_kernel<<<dim3(96, 4, 2), 256, 0, stream>>>(q, k, v, AOrh, AOrl);

    wo_swz_kernel<<<dim3(96), 256, 0, stream>>>(Wo, WOrh, WOrl);
    oproj_mfma_kernel<<<dim3(12, 8, 8), 256, 0, stream>>>(AOrh, AOrl, WOrh, WOrl, part);
    reduce8_kernel<<<dim3(768), 256, 0, stream>>>(part, (float*)d_out);
}